// Round 23
// baseline (329.226 us; speedup 1.0000x reference)
//
#include <hip/hip_runtime.h>
#include <math.h>

#define NB 32
#define NG 500
#define NP 500
#define ND 128
#define NH 8
#define NQK 16
#define NE 8
#define NFF 512
#define NT 16000   // B*G tokens

typedef __attribute__((ext_vector_type(8))) short bf16x8;
typedef __attribute__((ext_vector_type(4))) float f32x4;

static __device__ __forceinline__ unsigned short f2bf(float f) {
  unsigned int u = __float_as_uint(f);
  unsigned int r = (u + 0x7FFFu + ((u >> 16) & 1u)) >> 16;
  return (unsigned short)r;
}
static __device__ __forceinline__ float bf2f(unsigned short h) {
  return __uint_as_float(((unsigned int)h) << 16);
}

// ---------------------------------------------------------------------------
// K/V projection f32 v2: 16-row blocks (1000 active) for latency cover.
// ---------------------------------------------------------------------------
__global__ __launch_bounds__(256) void k_kv(const float* __restrict__ enc,
                                            const float* __restrict__ Wk,
                                            const float* __restrict__ Wv,
                                            float* __restrict__ kbuf,
                                            float* __restrict__ vbuf) {
  int r0 = blockIdx.x * 16;
  int tid = threadIdx.x;
  __shared__ float encS[16][128];
  const float4* e4 = (const float4*)(enc + (size_t)r0 * 128);
  float4* s4 = (float4*)&encS[0][0];
#pragma unroll
  for (int i = 0; i < 2; i++) s4[tid + i * 256] = e4[tid + i * 256];
  __syncthreads();
  int cg = tid & 31, rg = tid >> 5;   // 8 row-groups x 2 rows
  int c0 = cg * 8;  // col 0..255: [K cols | V cols]
  const float* W0 = (c0 < 128) ? (Wk + c0) : (Wv + (c0 - 128));
  float acc[2][8] = {};
  for (int d = 0; d < 128; d++) {
    float a0 = encS[rg * 2 + 0][d];
    float a1 = encS[rg * 2 + 1][d];
    float4 wlo = *(const float4*)(W0 + d * 128);
    float4 whi = *(const float4*)(W0 + d * 128 + 4);
    float w[8] = {wlo.x, wlo.y, wlo.z, wlo.w, whi.x, whi.y, whi.z, whi.w};
#pragma unroll
    for (int j = 0; j < 8; j++) {
      acc[0][j] += a0 * w[j];
      acc[1][j] += a1 * w[j];
    }
  }
#pragma unroll
  for (int i = 0; i < 2; i++) {
    int r = r0 + rg * 2 + i;
    int b = r / 500;
    int p = r - b * 500;
    int cc = (c0 < 128) ? c0 : (c0 - 128);
    int h = cc >> 4, qk = cc & 15;
    float* dst = (c0 < 128 ? kbuf : vbuf) + ((size_t)(b * 8 + h) * 500 + p) * 16 + qk;
    *(float4*)dst = make_float4(acc[i][0], acc[i][1], acc[i][2], acc[i][3]);
    *(float4*)(dst + 4) = make_float4(acc[i][4], acc[i][5], acc[i][6], acc[i][7]);
  }
}

// ---------------------------------------------------------------------------
// graphQ[b][j] = graph[b] @ Wq[0:128, j]
// ---------------------------------------------------------------------------
__global__ void k_graphq(const float* __restrict__ graph,
                         const float* __restrict__ Wq,
                         float* __restrict__ gq) {
  int b = blockIdx.x, j = threadIdx.x;
  float s = 0.f;
  for (int d = 0; d < 128; d++) s += graph[b * 128 + d] * Wq[d * 128 + j];
  gq[b * 128 + j] = s;
}

// ---------------------------------------------------------------------------
// mask transpose: mT[b][p][g] = bf16(mask[b][g][p]); tiled 32x32 via LDS.
// ---------------------------------------------------------------------------
__global__ __launch_bounds__(256) void k_maskT(const float* __restrict__ mask,
                                               unsigned short* __restrict__ mT) {
  int b = blockIdx.z;
  int pt = blockIdx.x * 32, gt = blockIdx.y * 32;
  __shared__ float t[32][33];
  int tx = threadIdx.x & 31, ty = threadIdx.x >> 5;   // 32 x 8
#pragma unroll
  for (int i = 0; i < 32; i += 8) {
    int g = gt + ty + i, p = pt + tx;
    t[ty + i][tx] = (g < NG && p < NP) ? mask[((size_t)b * NG + g) * NP + p] : 0.f;
  }
  __syncthreads();
#pragma unroll
  for (int i = 0; i < 32; i += 8) {
    int p = pt + ty + i, g = gt + tx;
    if (p < NP && g < NG)
      mT[((size_t)b * NP + p) * NG + g] = f2bf(t[tx][ty + i]);
  }
}

// ---------------------------------------------------------------------------
// enc pack for probs MFMA B-operand: split-bf16 hi/lo fragments.
// ---------------------------------------------------------------------------
__global__ __launch_bounds__(64) void k_encpack(const float* __restrict__ enc,
                                                unsigned short* __restrict__ eph,
                                                unsigned short* __restrict__ epl) {
  int bid = blockIdx.x;           // 32 b * 128 tiles
  int b = bid >> 7;
  int t = bid & 127;
  int kt = t >> 5, nt = t & 31;
  int l = threadIdx.x;
  int kg = 4 * (l >> 4);
  int p = nt * 16 + (l & 15);
  size_t base = ((((size_t)b * 4 + kt) * 32 + nt) * 64 + l) * 8;
#pragma unroll
  for (int j = 0; j < 8; j++) {
    int k = kt * 32 + kg + (j & 3) + ((j >> 2) << 4);
    float v = (p < NP) ? enc[((size_t)b * NP + p) * ND + k] : 0.f;
    unsigned short hi = f2bf(v);
    eph[base + j] = hi;
    epl[base + j] = f2bf(v - bf2f(hi));
  }
}

// ---------------------------------------------------------------------------
// mh pack for MoE A-operand: split-bf16 hi/lo in fragment k-order per token.
// ---------------------------------------------------------------------------
__global__ __launch_bounds__(256) void k_mhpack(const float* __restrict__ mh,
                                                unsigned short* __restrict__ mhph,
                                                unsigned short* __restrict__ mhpl) {
  int t0 = blockIdx.x * 32;
  int tid = threadIdx.x;
  for (int idx = tid; idx < 512; idx += 256) {
    int tl = idx >> 4;            // token local 0..31
    int kt = (idx >> 2) & 3;
    int lr = idx & 3;
    int t = t0 + tl;
    const float* row = mh + (size_t)t * ND + kt * 32 + 4 * lr;
    float4 a = *(const float4*)row;
    float4 b = *(const float4*)(row + 16);
    float v[8] = {a.x, a.y, a.z, a.w, b.x, b.y, b.z, b.w};
    size_t base = (((size_t)t * 4 + kt) * 4 + lr) * 8;
    unsigned short h[8], lo[8];
#pragma unroll
    for (int j = 0; j < 8; j++) {
      h[j] = f2bf(v[j]);
      lo[j] = f2bf(v[j] - bf2f(h[j]));
    }
    *(unsigned long long*)(mhph + base) = *(unsigned long long*)(&h[0]);
    *(unsigned long long*)(mhph + base + 4) = *(unsigned long long*)(&h[4]);
    *(unsigned long long*)(mhpl + base) = *(unsigned long long*)(&lo[0]);
    *(unsigned long long*)(mhpl + base + 4) = *(unsigned long long*)(&lo[4]);
  }
}

// ---------------------------------------------------------------------------
// attention v8: 128-thread blocks, 2 g-rows per thread SHARING all LDS reads
// (halves LDS instructions per g; 4 blocks/CU keeps 8 waves/CU).
// ---------------------------------------------------------------------------
__global__ __launch_bounds__(128) void k_attn(const float* __restrict__ kbuf,
                                              const float* __restrict__ vbuf,
                                              const float* __restrict__ capacity,
                                              const float* __restrict__ gq,
                                              const float* __restrict__ Wq,
                                              const unsigned short* __restrict__ mT,
                                              float* __restrict__ att) {
  int d = blockIdx.x;            // 0..255
  int xc = d & 7, kk = d >> 3;
  int b = ((kk >> 3) << 3) | xc; // all 8 h of b share XCD residue class
  int h = kk & 7;
  int bh = b * 8 + h;
  int half = blockIdx.y;         // 0..1
  int tid = threadIdx.x;         // 0..127
  __shared__ float2 AB[NP];
  __shared__ float vsh[NP][16];
  const float4* vp = (const float4*)(vbuf + (size_t)bh * NP * 16);
  float4* v4 = (float4*)&vsh[0][0];
  for (int i = tid; i < NP * 4; i += 128) v4[i] = vp[i];
  float gqv[16], wql[16];
#pragma unroll
  for (int j = 0; j < 16; j++) {
    gqv[j] = gq[b * 128 + h * 16 + j];
    wql[j] = Wq[128 * 128 + h * 16 + j];
  }
  const float4* kp = (const float4*)(kbuf + (size_t)bh * NP * 16);
  for (int p = tid; p < NP; p += 128) {
    float4 k0 = kp[p * 4 + 0], k1 = kp[p * 4 + 1];
    float4 k2 = kp[p * 4 + 2], k3 = kp[p * 4 + 3];
    float kv[16] = {k0.x, k0.y, k0.z, k0.w, k1.x, k1.y, k1.z, k1.w,
                    k2.x, k2.y, k2.z, k2.w, k3.x, k3.y, k3.z, k3.w};
    float a = 0.f, bb = 0.f;
#pragma unroll
    for (int j = 0; j < 16; j++) { a += gqv[j] * kv[j]; bb += wql[j] * kv[j]; }
    AB[p] = make_float2(a * 0.25f, bb * 0.25f);
  }
  __syncthreads();
  if (tid < 125) {
    int g0 = half * 250 + tid;
    int g1 = g0 + 125;
    float cap0 = capacity[b * NG + g0];
    float cap1 = capacity[b * NG + g1];
    float l0 = 0.f, l1 = 0.f;
    float o0[16] = {}, o1[16] = {};
    const unsigned short* mTb = mT + (size_t)b * NP * NG;
    for (int p = 0; p < NP; p++) {
      float2 ab = AB[p];
      float mv0 = bf2f(mTb[(size_t)p * NG + g0]);
      float mv1 = bf2f(mTb[(size_t)p * NG + g1]);
      float e0 = __expf(fmaf(cap0, ab.y, ab.x) + mv0);
      float e1 = __expf(fmaf(cap1, ab.y, ab.x) + mv1);
      l0 += e0;
      l1 += e1;
      const float4* vr = (const float4*)(&vsh[p][0]);
      float4 va = vr[0], vb = vr[1], vc = vr[2], vd = vr[3];
      o0[0] += e0 * va.x;  o0[1] += e0 * va.y;  o0[2] += e0 * va.z;  o0[3] += e0 * va.w;
      o0[4] += e0 * vb.x;  o0[5] += e0 * vb.y;  o0[6] += e0 * vb.z;  o0[7] += e0 * vb.w;
      o0[8] += e0 * vc.x;  o0[9] += e0 * vc.y;  o0[10] += e0 * vc.z; o0[11] += e0 * vc.w;
      o0[12] += e0 * vd.x; o0[13] += e0 * vd.y; o0[14] += e0 * vd.z; o0[15] += e0 * vd.w;
      o1[0] += e1 * va.x;  o1[1] += e1 * va.y;  o1[2] += e1 * va.z;  o1[3] += e1 * va.w;
      o1[4] += e1 * vb.x;  o1[5] += e1 * vb.y;  o1[6] += e1 * vb.z;  o1[7] += e1 * vb.w;
      o1[8] += e1 * vc.x;  o1[9] += e1 * vc.y;  o1[10] += e1 * vc.z; o1[11] += e1 * vc.w;
      o1[12] += e1 * vd.x; o1[13] += e1 * vd.y; o1[14] += e1 * vd.z; o1[15] += e1 * vd.w;
    }
    float inv0 = 1.f / l0;
    float inv1 = 1.f / l1;
    float* orow0 = att + ((size_t)(b * NG + g0)) * 128 + h * 16;
    float* orow1 = att + ((size_t)(b * NG + g1)) * 128 + h * 16;
#pragma unroll
    for (int j = 0; j < 16; j++) orow0[j] = o0[j] * inv0;
#pragma unroll
    for (int j = 0; j < 16; j++) orow1[j] = o1[j] * inv1;
  }
}

// ---------------------------------------------------------------------------
// mh = att(16000x128) @ Wcomb(128x128); block 32 rows, thread 2r x 8c
// ---------------------------------------------------------------------------
__global__ __launch_bounds__(256) void k_comb(const float* __restrict__ att,
                                              const float* __restrict__ Wc,
                                              float* __restrict__ mh) {
  int r0 = blockIdx.x * 32;
  int tid = threadIdx.x;
  __shared__ float aS[32][130];
  for (int idx = tid; idx < 32 * 32; idx += 256) {
    int r = idx >> 5, dg = idx & 31;
    float4 v = ((const float4*)att)[(size_t)(r0 + r) * 32 + dg];
    aS[r][dg * 4 + 0] = v.x; aS[r][dg * 4 + 1] = v.y;
    aS[r][dg * 4 + 2] = v.z; aS[r][dg * 4 + 3] = v.w;
  }
  __syncthreads();
  int cg = tid & 15, rg = tid >> 4;
  float acc[2][8] = {};
  for (int d = 0; d < 128; d++) {
    float a0 = aS[rg * 2 + 0][d];
    float a1 = aS[rg * 2 + 1][d];
    float4 wlo = *(const float4*)(Wc + d * 128 + cg * 8);
    float4 whi = *(const float4*)(Wc + d * 128 + cg * 8 + 4);
    float w[8] = {wlo.x, wlo.y, wlo.z, wlo.w, whi.x, whi.y, whi.z, whi.w};
#pragma unroll
    for (int j = 0; j < 8; j++) {
      acc[0][j] += a0 * w[j];
      acc[1][j] += a1 * w[j];
    }
  }
#pragma unroll
  for (int i = 0; i < 2; i++) {
    float* dst = mh + (size_t)(r0 + rg * 2 + i) * 128 + cg * 8;
    *(float4*)dst = make_float4(acc[i][0], acc[i][1], acc[i][2], acc[i][3]);
    *(float4*)(dst + 4) = make_float4(acc[i][4], acc[i][5], acc[i][6], acc[i][7]);
  }
}

// ---------------------------------------------------------------------------
// gating: logits, top-2, softmax gates; hierarchical bucketing
// ---------------------------------------------------------------------------
__global__ __launch_bounds__(256) void k_gate(const float* __restrict__ mh,
                                              const float* __restrict__ wg,
                                              int* __restrict__ tlist,
                                              float* __restrict__ glist,
                                              int* __restrict__ cnt,
                                              float* __restrict__ imp) {
  int t0 = blockIdx.x * 256;
  int tid = threadIdx.x;
  __shared__ float wgS[128 * 8];
  __shared__ int lcnt[8];
  __shared__ float limp[8];
  __shared__ int lbase[8];
  for (int i = tid; i < 1024; i += 256) wgS[i] = wg[i];
  if (tid < 8) { lcnt[tid] = 0; limp[tid] = 0.f; }
  __syncthreads();
  int t = t0 + tid;
  bool ok = (t < NT);
  int i0 = 0, i1 = 0, r0 = 0, r1 = 0;
  float g0 = 0.f, g1 = 0.f;
  if (ok) {
    float lg[8] = {};
    const float* row = mh + (size_t)t * ND;
    for (int d = 0; d < ND; d += 4) {
      float4 x4 = *(const float4*)(row + d);
      float xs[4] = {x4.x, x4.y, x4.z, x4.w};
#pragma unroll
      for (int u = 0; u < 4; u++)
#pragma unroll
        for (int k = 0; k < 8; k++) lg[k] += xs[u] * wgS[(d + u) * 8 + k];
    }
    float v0 = -1e30f, v1 = -1e30f;
#pragma unroll
    for (int k = 0; k < 8; k++) {
      float l = lg[k];
      if (l > v0) { v1 = v0; i1 = i0; v0 = l; i0 = k; }
      else if (l > v1) { v1 = l; i1 = k; }
    }
    float ex = __expf(v1 - v0);
    float den = 1.0f + ex;
    g0 = 1.0f / den; g1 = ex / den;
    atomicAdd(&limp[i0], g0);
    atomicAdd(&limp[i1], g1);
    r0 = atomicAdd(&lcnt[i0], 1);
    r1 = atomicAdd(&lcnt[i1], 1);
  }
  __syncthreads();
  if (tid < 8) {
    lbase[tid] = atomicAdd(&cnt[tid], lcnt[tid]);
    atomicAdd(&imp[tid], limp[tid]);
  }
  __syncthreads();
  if (ok) {
    int p0 = lbase[i0] + r0;
    tlist[i0 * NT + p0] = t; glist[i0 * NT + p0] = g0;
    int p1 = lbase[i1] + r1;
    tlist[i1 * NT + p1] = t; glist[i1 * NT + p1] = g1;
  }
}

// ---------------------------------------------------------------------------
// Pack W1/W2 into fragment-ordered bf16 hi/lo for 16x16x32 MFMA B-operand.
// ---------------------------------------------------------------------------
__global__ __launch_bounds__(64) void k_wpack(const float* __restrict__ W1,
                                              const float* __restrict__ W2,
                                              unsigned short* __restrict__ w1h,
                                              unsigned short* __restrict__ w1l,
                                              unsigned short* __restrict__ w2h,
                                              unsigned short* __restrict__ w2l) {
  int bid = blockIdx.x;           // 8 experts * 256 tiles
  int e = bid >> 8;
  int t = bid & 255;
  int l = threadIdx.x;
  int kg = 4 * (l >> 4);
  if (t < 128) {
    int kt = t >> 5, nt = t & 31;
    const float* src = W1 + (size_t)e * 128 * 512;
    size_t base = ((((size_t)e * 4 + kt) * 32 + nt) * 64 + l) * 8;
    int n = nt * 16 + (l & 15);
#pragma unroll
    for (int j = 0; j < 8; j++) {
      int k = kt * 32 + kg + (j & 3) + ((j >> 2) << 4);
      float v = src[(size_t)k * 512 + n];
      unsigned short hi = f2bf(v);
      w1h[base + j] = hi;
      w1l[base + j] = f2bf(v - bf2f(hi));
    }
  } else {
    int tt = t - 128;
    int kt = tt >> 3, nt = tt & 7;
    const float* src = W2 + (size_t)e * 512 * 128;
    size_t base = ((((size_t)e * 16 + kt) * 8 + nt) * 64 + l) * 8;
    int n = nt * 16 + (l & 15);
#pragma unroll
    for (int j = 0; j < 8; j++) {
      int k = kt * 32 + kg + (j & 3) + ((j >> 2) << 4);
      float v = src[(size_t)k * 128 + n];
      unsigned short hi = f2bf(v);
      w2h[base + j] = hi;
      w2l[base + j] = f2bf(v - bf2f(hi));
    }
  }
}

// ---------------------------------------------------------------------------
// MoE expert FFN v11: z=2 half-split with sequential 2-chunk loop, packed A.
// ---------------------------------------------------------------------------
__global__ __launch_bounds__(256) void k_moe(const unsigned short* __restrict__ mhph,
                                             const unsigned short* __restrict__ mhpl,
                                             const unsigned short* __restrict__ w1h,
                                             const unsigned short* __restrict__ w1l,
                                             const unsigned short* __restrict__ w2h,
                                             const unsigned short* __restrict__ w2l,
                                             const float* __restrict__ b1,
                                             const float* __restrict__ b2,
                                             const int* __restrict__ tlist,
                                             const float* __restrict__ glist,
                                             const int* __restrict__ cnt,
                                             float* __restrict__ acc) {
  int e = blockIdx.y;
  int z = blockIdx.z;             // f-half 0..1
  int n = cnt[e];
  int t0 = blockIdx.x * 32;
  if (t0 >= n) return;
  int tid = threadIdx.x;
  int wq = tid >> 6;              // 0..3: N-quarter
  int l = tid & 63;
  int lr = l >> 4;
  __shared__ int rT[32];
  __shared__ float rG[32];
  __shared__ unsigned short hH[32][132];
  __shared__ unsigned short hL[32][132];
  if (tid < 32) {
    int ok = (t0 + tid) < n;
    rT[tid] = ok ? tlist[e * NT + t0 + tid] : -1;
    rG[tid] = ok ? glist[e * NT + t0 + tid] : 0.f;
  }
  __syncthreads();

  int kg = 4 * lr;
  bf16x8 Ah[2][4], Al[2][4];
#pragma unroll
  for (int m = 0; m < 2; m++) {
    int myrow = m * 16 + (l & 15);
    int mytok = rT[myrow];
#pragma unroll
    for (int kt = 0; kt < 4; kt++) {
      if (mytok >= 0) {
        size_t base = (((size_t)mytok * 4 + kt) * 4 + lr) * 8;
        Ah[m][kt] = *(const bf16x8*)(mhph + base);
        Al[m][kt] = *(const bf16x8*)(mhpl + base);
      } else {
        Ah[m][kt] = (bf16x8){0, 0, 0, 0, 0, 0, 0, 0};
        Al[m][kt] = (bf16x8){0, 0, 0, 0, 0, 0, 0, 0};
      }
    }
  }

  f32x4 zero4 = {0.f, 0.f, 0.f, 0.f};
  f32x4 yB[2][2] = {{zero4, zero4}, {zero4, zero4}};

  for (int cc = 0; cc < 2; cc++) {
    int c = z * 2 + cc;           // f-chunk 0..3
    f32x4 accA[2][2] = {{zero4, zero4}, {zero4, zero4}};
#pragma unroll
    for (int kt = 0; kt < 4; kt++) {
      bf16x8 bh[2], bl[2];
#pragma unroll
      for (int nt = 0; nt < 2; nt++) {
        int ntg = c * 8 + wq * 2 + nt;
        size_t fo = ((((size_t)e * 4 + kt) * 32 + ntg) * 64 + l) * 8;
        bh[nt] = *(const bf16x8*)(w1h + fo);
        bl[nt] = *(const bf16x8*)(w1l + fo);
      }
#pragma unroll
      for (int nt = 0; nt < 2; nt++)
#pragma unroll
        for (int m = 0; m < 2; m++) {
          accA[m][nt] = __builtin_amdgcn_mfma_f32_16x16x32_bf16(Ah[m][kt], bh[nt], accA[m][nt], 0, 0, 0);
          accA[m][nt] = __builtin_amdgcn_mfma_f32_16x16x32_bf16(Ah[m][kt], bl[nt], accA[m][nt], 0, 0, 0);
          accA[m][nt] = __builtin_amdgcn_mfma_f32_16x16x32_bf16(Al[m][kt], bh[nt], accA[m][nt], 0, 0, 0);
        }
    }
    __syncthreads();
#pragma unroll
    for (int nt = 0; nt < 2; nt++) {
      int nloc = wq * 32 + nt * 16 + (l & 15);
      float bv = b1[e * NFF + c * 128 + nloc];
#pragma unroll
      for (int m = 0; m < 2; m++)
#pragma unroll
        for (int r = 0; r < 4; r++) {
          int row = m * 16 + (l >> 4) * 4 + r;
          float hv = fmaxf(accA[m][nt][r] + bv, 0.f);
          unsigned short hi = f2bf(hv);
          hH[row][nloc] = hi;
          hL[row][nloc] = f2bf(hv - bf2f(hi));
        }
    }
    __syncthreads();
#pragma unroll
    for (int kt = 0; kt < 4; kt++) {
      int kb = kt * 32 + kg;
      bf16x8 ah2[2], al2[2];
#pragma unroll
      for (int m = 0; m < 2; m++) {
        int r2 = m * 16 + (l & 15);
        union { unsigned long long u[2]; bf16x8 v; } ua, ub;
        ua.u[0] = *(const unsigned long long*)(&hH[r2][kb]);
        ua.u[1] = *(const unsigned long long*)(&hH[r2][kb + 16]);
        ub.u[0] = *(const unsigned long long*)(&hL[r2][kb]);
        ub.u[1] = *(const unsigned long long*)(&hL[r2][kb + 16]);
        ah2[m] = ua.v; al2[m] = ub.v;
      }
      bf16x8 wh[2], wl[2];
#pragma unroll
      for (int nt = 0; nt < 2; nt++) {
        int ntg = wq * 2 + nt;
        size_t fo = ((((size_t)e * 16 + (c * 4 + kt)) * 8 + ntg) * 64 + l) * 8;
        wh[nt] = *(const bf16x8*)(w2h + fo);
        wl[nt] = *(const bf16x8*)(w2l + fo);
      }
#pragma unroll
      for (int nt = 0; nt < 2; nt++)
#pragma unroll
        for (int m = 0; m < 2; m++) {
          yB[m][nt] = __builtin_amdgcn_mfma_f32_16x16x32_bf16(ah2[m], wh[nt], yB[m][nt], 0, 0, 0);
          yB[m][nt] = __builtin_amdgcn_mfma_f32_16x16x32_bf16(ah2[m], wl[nt], yB[m][nt], 0, 0, 0);
          yB[m][nt] = __builtin_amdgcn_mfma_f32_16x16x32_bf16(al2[m], wh[nt], yB[m][nt], 0, 0, 0);
        }
    }
    __syncthreads();
  }
  float bsel = (z == 0) ? 1.f : 0.f;
#pragma unroll
  for (int nt = 0; nt < 2; nt++) {
    int d = (wq * 2 + nt) * 16 + (l & 15);
    float b2v = bsel * b2[e * ND + d];
#pragma unroll
    for (int m = 0; m < 2; m++)
#pragma unroll
      for (int r = 0; r < 4; r++) {
        int row = m * 16 + (l >> 4) * 4 + r;
        int tok = rT[row];
        if (tok >= 0)
          atomicAdd(acc + (size_t)tok * ND + d, rG[row] * (yB[m][nt][r] + b2v));
      }
  }
}

// ---------------------------------------------------------------------------
// moed_loss from importance
// ---------------------------------------------------------------------------
__global__ void k_loss(const float* __restrict__ imp, float* __restrict__ out) {
  if (threadIdx.x == 0 && blockIdx.x == 0) {
    float s = 0.f;
    for (int k = 0; k < 8; k++) s += imp[k];
    float mu = s * 0.125f;
    float v = 0.f;
    for (int k = 0; k < 8; k++) { float d = imp[k] - mu; v += d * d; }
    v *= (1.0f / 7.0f);
    out[8000000] = v / (mu * mu + 1e-10f);
  }
}

// ---------------------------------------------------------------------------
// added = mh + moe; instance-norm over G per (b,d); block = (b, 16-d chunk)
// ---------------------------------------------------------------------------
__global__ __launch_bounds__(256) void k_norm(const float* __restrict__ mh,
                                              const float* __restrict__ moe,
                                              const float* __restrict__ nw,
                                              const float* __restrict__ nb,
                                              float* __restrict__ outn) {
  int b = blockIdx.y;
  int d0 = blockIdx.x * 16;
  int tid = threadIdx.x;
  int dl = tid & 15, gs = tid >> 4;
  int d = d0 + dl;
  float s1 = 0.f, s2 = 0.f;
  for (int g = gs; g < NG; g += 16) {
    int idx = (b * NG + g) * ND + d;
    float x = mh[idx] + moe[idx];
    s1 += x; s2 += x * x;
  }
  __shared__ float r1[16][17], r2[16][17];
  __shared__ float sw[16], sb[16];
  r1[gs][dl] = s1; r2[gs][dl] = s2;
  __syncthreads();
  if (gs == 0) {
    float a = 0.f, q = 0.f;
    for (int k = 0; k < 16; k++) { a += r1[k][dl]; q += r2[k][dl]; }
    float mu = a * (1.0f / NG);
    float var = q * (1.0f / NG) - mu * mu;
    float rs = rsqrtf(var + 1e-5f);
    float w = nw[d] * rs;
    sw[dl] = w;
    sb[dl] = nb[d] - mu * w;
  }
  __syncthreads();
  float w = sw[dl], bb = sb[dl];
  for (int g = gs; g < NG; g += 16) {
    int idx = (b * NG + g) * ND + d;
    float x = mh[idx] + moe[idx];
    outn[idx] = x * w + bb;
  }
}

// ---------------------------------------------------------------------------
// final probs v3: split-bf16 MFMA score GEMM (A=normed, B=packed enc),
// tanh-clip + mask + no-max softmax; block = 32 g x 512 p, 4 waves = p-quarters.
// ---------------------------------------------------------------------------
__global__ __launch_bounds__(256) void k_probs(const float* __restrict__ normed,
                                               const unsigned short* __restrict__ eph,
                                               const unsigned short* __restrict__ epl,
                                               const float* __restrict__ mask,
                                               float* __restrict__ out) {
  int b = blockIdx.y;
  int g0 = blockIdx.x * 32;
  int tid = threadIdx.x;
  int wq = tid >> 6;              // p-quarter
  int l = tid & 63;
  int col = l & 15, lr = l >> 4;
  int kg = 4 * lr;
  __shared__ float ps[4][32];

  bf16x8 Ah[2][4], Al[2][4];
#pragma unroll
  for (int m = 0; m < 2; m++) {
    int g = g0 + m * 16 + col;
#pragma unroll
    for (int kt = 0; kt < 4; kt++) {
      float v[8];
      if (g < NG) {
        const float* row = normed + ((size_t)b * NG + g) * ND + kt * 32 + kg;
        float4 a = *(const float4*)(row);
        float4 bb = *(const float4*)(row + 16);
        v[0] = a.x; v[1] = a.y; v[2] = a.z; v[3] = a.w;
        v[4] = bb.x; v[5] = bb.y; v[6] = bb.z; v[7] = bb.w;
      } else {
#pragma unroll
        for (int j = 0; j < 8; j++) v[j] = 0.f;
      }
#pragma unroll
      for (int j = 0; j < 8; j++) {
        unsigned short hi = f2bf(v[j]);
        Ah[m][kt][j] = (short)hi;
        Al[m][kt][j] = (short)f2bf(v[j] - bf2f(hi));
      }
    }
  }

  f32x4 zero4 = {0.f, 0.f, 0.f, 0.f};
  f32x4 acc[2][8];
#pragma unroll
  for (int m = 0; m < 2; m++)
#pragma unroll
    for (int nt = 0; nt < 8; nt++) acc[m][nt] = zero4;

#pragma unroll
  for (int kt = 0; kt < 4; kt++) {
#pragma unroll
    for (int nt = 0; nt < 8; nt++) {
      int ntg = wq * 8 + nt;
      size_t fo = ((((size_t)b * 4 + kt) * 32 + ntg) * 64 + l) * 8;
      bf16x8 bh = *(const bf16x8*)(eph + fo);
      bf16x8 bl = *(const bf16x8*)(epl + fo);
#pragma unroll
      for (int m = 0; m < 2; m++) {
        acc[m][nt] = __builtin_amdgcn_mfma_f32_16x16x32_bf16(Ah[m][kt], bh, acc[m][nt], 0, 0, 0);
        acc[m][nt] = __builtin_amdgcn_mfma_f32_16x16x32_bf16(Ah[m][kt], bl, acc[m][nt], 0, 0, 0);
        acc[m][nt] = __builtin_amdgcn_mfma_f32_16x16x32_bf16(Al[m][kt], bh, acc[m][nt], 0, 0, 0);
      }
    }
  }

  float psum[2][4] = {};
#pragma unroll
  for (int m = 0; m < 2; m++)
#pragma unroll
    for (int nt = 0; nt < 8; nt++) {
      int p = wq * 128 + nt * 16 + col;
#pragma unroll
      for (int r = 0; r < 4; r++) {
        int g = g0 + m * 16 + 4 * lr + r;
        float s = acc[m][nt][r];
        float x = s * (1.0f / 11.313708498984761f);
        float e2 = __expf(2.0f * x);
        float th = (e2 - 1.0f) / (e2 + 1.0f);
        float v;
        if (p < NP && g < NG)
          v = 10.0f * th + mask[((size_t)b * NG + g) * NP + p];
        else
          v = -1e30f;
        float e = __expf(v);
        acc[m][nt][r] = e;
        psum[m][r] += e;
      }
    }
#pragma unroll
  for (int m = 0; m < 2; m++)
#pragma unroll
    for (int r = 0; r < 4; r++) {
      float s = psum[m][r];
      s += __shfl_xor(s, 1);
      s += __shfl_xor(s, 2);
      s += __shfl_xor(s, 4);
      s += __shfl_xor(s, 8);
      psum[m][r] = s;
    }
  if (col == 0) {
#pragma unroll
    for (int m = 0; m < 2; m++)
#pragma unroll
      for (int r = 0; r < 4; r++)
        ps[wq][m * 16 + 4 * lr + r] = psum[m][r];
  }
  __syncthreads();
#pragma unroll
  for (int m = 0; m < 2; m++)
#pragma unroll
    for (int r = 0; r < 4; r++) {
      int rowl = m * 16 + 4 * lr + r;
      float tot = ps[0][rowl] + ps[1][rowl] + ps[2][rowl] + ps[3][rowl];
      float inv = 1.0f / tot;
      int g = g0 + rowl;
      if (g < NG) {
#pragma unroll
        for (int nt = 0; nt < 8; nt++) {
          int p = wq * 128 + nt * 16 + col;
          if (p < NP)
            out[((size_t)b * NG + g) * NP + p] = acc[m][nt][r] * inv;
        }
      }
    }
}

// ---------------------------------------------------------------------------
extern "C" void kernel_launch(void* const* d_in, const int* in_sizes, int n_in,
                              void* d_out, int out_size, void* d_ws, size_t ws_size,
                              hipStream_t stream) {
  const float* graph    = (const float*)d_in[0];
  const float* capacity = (const float*)d_in[1];
  const float* mask     = (const float*)d_in[2];
  const float* enc      = (const float*)d_in[3];
  const float* Wq       = (const float*)d_in[4];
  const float* Wk       = (const float*)d_in[5];
  const float* Wv       = (const float*)d_in[6];
  const float* Wc       = (const float*)d_in[7];
  const float* wg       = (const float*)d_in[8];
  const float* W1       = (const float*)d_in[9];
  const float* b1       = (const float*)d_in[10];
  const float* W2       = (const float*)d_in[11];
  const float* b2       = (const float*)d_in[12];
  const float* nw       = (const float*)d_in[13];
  const float* nb       = (const float*)d_in[14];
  float* out = (float*)d_out;
  float* ws = (float*)d_ws;

  float* kbuf = ws;                  // 2,048,000 f  (later reused as moe accum)
  float* vbuf = ws + 2048000;        // 2,048,000 f  (later reused as normed)
  float* att  = ws + 4096000;        // 2,048,000 f  (later reused as eph)
  float* mh   = ws + 6144000;        // 2,048,000 f
  float* gq   = ws + 8192000;        // 4096 f
  int*   tlist = (int*)(ws + 8196096);   // 8*16000 int
  float* glist = ws + 8324096;           // 8*16000 f
  int*   cnt  = (int*)(ws + 8452096);    // 8 int
  float* imp  = ws + 8452104;            // 8 f
  // packed bf16 weights (each 524288 ushorts = 262144 float-slots)
  unsigned short* w1h = (unsigned short*)(ws + 8452112);
  unsigned short* w1l = (unsigned short*)(ws + 8714256);
  unsigned short* w2h = (unsigned short*)(ws + 8976400);
  unsigned short* w2l = (unsigned short*)(ws + 9238544);
  // transposed bf16 mask: dead after k_attn -> reused as packed mh hi/lo
  unsigned short* mT = (unsigned short*)(ws + 9500688);
  unsigned short* mhph = mT;
  unsigned short* mhpl = mT + 2048000;
  // packed enc fragments: eph aliases att region (after comb); epl at tail
  unsigned short* eph = (unsigned short*)att;
  unsigned short* epl = (unsigned short*)(ws + 13500688);

  k_maskT<<<dim3(16, 16, 32), 256, 0, stream>>>(mask, mT);
  k_wpack<<<2048, 64, 0, stream>>>(W1, W2, w1h, w1l, w2h, w2l);
  k_kv<<<1000, 256, 0, stream>>>(enc, Wk, Wv, kbuf, vbuf);
  k_graphq<<<32, 128, 0, stream>>>(graph, Wq, gq);
  k_attn<<<dim3(256, 2), 128, 0, stream>>>(kbuf, vbuf, capacity, gq, Wq, mT, att);
  // k/v consumed; reuse kbuf as MoE accumulator
  hipMemsetAsync(kbuf, 0, 2048000 * sizeof(float), stream);
  hipMemsetAsync(cnt, 0, 64, stream);  // cnt[8] + imp[8]
  k_comb<<<500, 256, 0, stream>>>(att, Wc, mh);
  // att consumed -> eph; mT consumed -> packed mh
  k_encpack<<<4096, 64, 0, stream>>>(enc, eph, epl);
  k_mhpack<<<500, 256, 0, stream>>>(mh, mhph, mhpl);
  k_gate<<<63, 256, 0, stream>>>(mh, wg, tlist, glist, cnt, imp);
  k_moe<<<dim3(500, 8, 2), 256, 0, stream>>>(mhph, mhpl, w1h, w1l, w2h, w2l,
                                             b1, b2, tlist, glist, cnt, kbuf);
  k_loss<<<1, 64, 0, stream>>>(imp, out);
  k_norm<<<dim3(8, 32), 256, 0, stream>>>(mh, kbuf, nw, nb, vbuf);
  k_probs<<<dim3(16, 32), 256, 0, stream>>>(vbuf, eph, epl, mask, out);
}

// Round 24
// 285.574 us; speedup vs baseline: 1.1529x; 1.1529x over previous
//
#include <hip/hip_runtime.h>
#include <math.h>

#define NB 32
#define NG 500
#define NP 500
#define ND 128
#define NH 8
#define NQK 16
#define NE 8
#define NFF 512
#define NT 16000   // B*G tokens

typedef __attribute__((ext_vector_type(8))) short bf16x8;
typedef __attribute__((ext_vector_type(4))) float f32x4;

static __device__ __forceinline__ unsigned short f2bf(float f) {
  unsigned int u = __float_as_uint(f);
  unsigned int r = (u + 0x7FFFu + ((u >> 16) & 1u)) >> 16;
  return (unsigned short)r;
}
static __device__ __forceinline__ float bf2f(unsigned short h) {
  return __uint_as_float(((unsigned int)h) << 16);
}

// ---------------------------------------------------------------------------
// K/V projection f32 v2: 16-row blocks (1000 active) for latency cover.
// ---------------------------------------------------------------------------
__global__ __launch_bounds__(256) void k_kv(const float* __restrict__ enc,
                                            const float* __restrict__ Wk,
                                            const float* __restrict__ Wv,
                                            float* __restrict__ kbuf,
                                            float* __restrict__ vbuf) {
  int r0 = blockIdx.x * 16;
  int tid = threadIdx.x;
  __shared__ float encS[16][128];
  const float4* e4 = (const float4*)(enc + (size_t)r0 * 128);
  float4* s4 = (float4*)&encS[0][0];
#pragma unroll
  for (int i = 0; i < 2; i++) s4[tid + i * 256] = e4[tid + i * 256];
  __syncthreads();
  int cg = tid & 31, rg = tid >> 5;   // 8 row-groups x 2 rows
  int c0 = cg * 8;  // col 0..255: [K cols | V cols]
  const float* W0 = (c0 < 128) ? (Wk + c0) : (Wv + (c0 - 128));
  float acc[2][8] = {};
  for (int d = 0; d < 128; d++) {
    float a0 = encS[rg * 2 + 0][d];
    float a1 = encS[rg * 2 + 1][d];
    float4 wlo = *(const float4*)(W0 + d * 128);
    float4 whi = *(const float4*)(W0 + d * 128 + 4);
    float w[8] = {wlo.x, wlo.y, wlo.z, wlo.w, whi.x, whi.y, whi.z, whi.w};
#pragma unroll
    for (int j = 0; j < 8; j++) {
      acc[0][j] += a0 * w[j];
      acc[1][j] += a1 * w[j];
    }
  }
#pragma unroll
  for (int i = 0; i < 2; i++) {
    int r = r0 + rg * 2 + i;
    int b = r / 500;
    int p = r - b * 500;
    int cc = (c0 < 128) ? c0 : (c0 - 128);
    int h = cc >> 4, qk = cc & 15;
    float* dst = (c0 < 128 ? kbuf : vbuf) + ((size_t)(b * 8 + h) * 500 + p) * 16 + qk;
    *(float4*)dst = make_float4(acc[i][0], acc[i][1], acc[i][2], acc[i][3]);
    *(float4*)(dst + 4) = make_float4(acc[i][4], acc[i][5], acc[i][6], acc[i][7]);
  }
}

// ---------------------------------------------------------------------------
// graphQ[b][j] = graph[b] @ Wq[0:128, j]
// ---------------------------------------------------------------------------
__global__ void k_graphq(const float* __restrict__ graph,
                         const float* __restrict__ Wq,
                         float* __restrict__ gq) {
  int b = blockIdx.x, j = threadIdx.x;
  float s = 0.f;
  for (int d = 0; d < 128; d++) s += graph[b * 128 + d] * Wq[d * 128 + j];
  gq[b * 128 + j] = s;
}

// ---------------------------------------------------------------------------
// mask transpose: mT[b][p][g] = bf16(mask[b][g][p]); tiled 32x32 via LDS.
// ---------------------------------------------------------------------------
__global__ __launch_bounds__(256) void k_maskT(const float* __restrict__ mask,
                                               unsigned short* __restrict__ mT) {
  int b = blockIdx.z;
  int pt = blockIdx.x * 32, gt = blockIdx.y * 32;
  __shared__ float t[32][33];
  int tx = threadIdx.x & 31, ty = threadIdx.x >> 5;   // 32 x 8
#pragma unroll
  for (int i = 0; i < 32; i += 8) {
    int g = gt + ty + i, p = pt + tx;
    t[ty + i][tx] = (g < NG && p < NP) ? mask[((size_t)b * NG + g) * NP + p] : 0.f;
  }
  __syncthreads();
#pragma unroll
  for (int i = 0; i < 32; i += 8) {
    int p = pt + ty + i, g = gt + tx;
    if (p < NP && g < NG)
      mT[((size_t)b * NP + p) * NG + g] = f2bf(t[tx][ty + i]);
  }
}

// ---------------------------------------------------------------------------
// enc pack for probs MFMA B-operand: split-bf16 hi/lo fragments.
// ---------------------------------------------------------------------------
__global__ __launch_bounds__(64) void k_encpack(const float* __restrict__ enc,
                                                unsigned short* __restrict__ eph,
                                                unsigned short* __restrict__ epl) {
  int bid = blockIdx.x;           // 32 b * 128 tiles
  int b = bid >> 7;
  int t = bid & 127;
  int kt = t >> 5, nt = t & 31;
  int l = threadIdx.x;
  int kg = 4 * (l >> 4);
  int p = nt * 16 + (l & 15);
  size_t base = ((((size_t)b * 4 + kt) * 32 + nt) * 64 + l) * 8;
#pragma unroll
  for (int j = 0; j < 8; j++) {
    int k = kt * 32 + kg + (j & 3) + ((j >> 2) << 4);
    float v = (p < NP) ? enc[((size_t)b * NP + p) * ND + k] : 0.f;
    unsigned short hi = f2bf(v);
    eph[base + j] = hi;
    epl[base + j] = f2bf(v - bf2f(hi));
  }
}

// ---------------------------------------------------------------------------
// mh pack for MoE A-operand: split-bf16 hi/lo in fragment k-order per token.
// ---------------------------------------------------------------------------
__global__ __launch_bounds__(256) void k_mhpack(const float* __restrict__ mh,
                                                unsigned short* __restrict__ mhph,
                                                unsigned short* __restrict__ mhpl) {
  int t0 = blockIdx.x * 32;
  int tid = threadIdx.x;
  for (int idx = tid; idx < 512; idx += 256) {
    int tl = idx >> 4;            // token local 0..31
    int kt = (idx >> 2) & 3;
    int lr = idx & 3;
    int t = t0 + tl;
    const float* row = mh + (size_t)t * ND + kt * 32 + 4 * lr;
    float4 a = *(const float4*)row;
    float4 b = *(const float4*)(row + 16);
    float v[8] = {a.x, a.y, a.z, a.w, b.x, b.y, b.z, b.w};
    size_t base = (((size_t)t * 4 + kt) * 4 + lr) * 8;
    unsigned short h[8], lo[8];
#pragma unroll
    for (int j = 0; j < 8; j++) {
      h[j] = f2bf(v[j]);
      lo[j] = f2bf(v[j] - bf2f(h[j]));
    }
    *(unsigned long long*)(mhph + base) = *(unsigned long long*)(&h[0]);
    *(unsigned long long*)(mhph + base + 4) = *(unsigned long long*)(&h[4]);
    *(unsigned long long*)(mhpl + base) = *(unsigned long long*)(&lo[0]);
    *(unsigned long long*)(mhpl + base + 4) = *(unsigned long long*)(&lo[4]);
  }
}

// ---------------------------------------------------------------------------
// attention v7 (known-good best): factorized scores + transposed mask,
// HALF-G, p-UNROLL x4.
// ---------------------------------------------------------------------------
__global__ __launch_bounds__(256) void k_attn(const float* __restrict__ kbuf,
                                              const float* __restrict__ vbuf,
                                              const float* __restrict__ capacity,
                                              const float* __restrict__ gq,
                                              const float* __restrict__ Wq,
                                              const unsigned short* __restrict__ mT,
                                              float* __restrict__ att) {
  int d = blockIdx.x;            // 0..255
  int xc = d & 7, kk = d >> 3;
  int b = ((kk >> 3) << 3) | xc; // all 8 h of b share XCD residue class
  int h = kk & 7;
  int bh = b * 8 + h;
  int half = blockIdx.y;         // 0..1
  int tid = threadIdx.x;
  __shared__ float2 AB[NP];
  __shared__ float vsh[NP][16];
  const float4* vp = (const float4*)(vbuf + (size_t)bh * NP * 16);
  float4* v4 = (float4*)&vsh[0][0];
  for (int i = tid; i < NP * 4; i += 256) v4[i] = vp[i];
  float gqv[16], wql[16];
#pragma unroll
  for (int j = 0; j < 16; j++) {
    gqv[j] = gq[b * 128 + h * 16 + j];
    wql[j] = Wq[128 * 128 + h * 16 + j];
  }
  const float4* kp = (const float4*)(kbuf + (size_t)bh * NP * 16);
  for (int p = tid; p < NP; p += 256) {
    float4 k0 = kp[p * 4 + 0], k1 = kp[p * 4 + 1];
    float4 k2 = kp[p * 4 + 2], k3 = kp[p * 4 + 3];
    float kv[16] = {k0.x, k0.y, k0.z, k0.w, k1.x, k1.y, k1.z, k1.w,
                    k2.x, k2.y, k2.z, k2.w, k3.x, k3.y, k3.z, k3.w};
    float a = 0.f, bb = 0.f;
#pragma unroll
    for (int j = 0; j < 16; j++) { a += gqv[j] * kv[j]; bb += wql[j] * kv[j]; }
    AB[p] = make_float2(a * 0.25f, bb * 0.25f);
  }
  __syncthreads();
  if (tid < 250) {
    int g = half * 250 + tid;
    float cap = capacity[b * NG + g];
    float l = 0.f;
    float o[16] = {};
    const unsigned short* mTb = mT + (size_t)b * NP * NG + g;
    for (int p = 0; p < NP; p += 4) {
      float mv0 = bf2f(mTb[(size_t)(p + 0) * NG]);
      float mv1 = bf2f(mTb[(size_t)(p + 1) * NG]);
      float mv2 = bf2f(mTb[(size_t)(p + 2) * NG]);
      float mv3 = bf2f(mTb[(size_t)(p + 3) * NG]);
      float2 ab0 = AB[p + 0];
      float2 ab1 = AB[p + 1];
      float2 ab2 = AB[p + 2];
      float2 ab3 = AB[p + 3];
      float e0 = __expf(fmaf(cap, ab0.y, ab0.x) + mv0);
      float e1 = __expf(fmaf(cap, ab1.y, ab1.x) + mv1);
      float e2 = __expf(fmaf(cap, ab2.y, ab2.x) + mv2);
      float e3 = __expf(fmaf(cap, ab3.y, ab3.x) + mv3);
      l += (e0 + e1) + (e2 + e3);
#pragma unroll
      for (int u = 0; u < 4; u++) {
        float e = (u == 0) ? e0 : (u == 1) ? e1 : (u == 2) ? e2 : e3;
        const float4* vr = (const float4*)(&vsh[p + u][0]);
        float4 va = vr[0], vb = vr[1], vc = vr[2], vd = vr[3];
        o[0] += e * va.x;  o[1] += e * va.y;  o[2] += e * va.z;  o[3] += e * va.w;
        o[4] += e * vb.x;  o[5] += e * vb.y;  o[6] += e * vb.z;  o[7] += e * vb.w;
        o[8] += e * vc.x;  o[9] += e * vc.y;  o[10] += e * vc.z; o[11] += e * vc.w;
        o[12] += e * vd.x; o[13] += e * vd.y; o[14] += e * vd.z; o[15] += e * vd.w;
      }
    }
    float inv = 1.f / l;
    float* orow = att + ((size_t)(b * NG + g)) * 128 + h * 16;
#pragma unroll
    for (int j = 0; j < 16; j++) orow[j] = o[j] * inv;
  }
}

// ---------------------------------------------------------------------------
// mh = att(16000x128) @ Wcomb(128x128); block 32 rows, thread 2r x 8c
// ---------------------------------------------------------------------------
__global__ __launch_bounds__(256) void k_comb(const float* __restrict__ att,
                                              const float* __restrict__ Wc,
                                              float* __restrict__ mh) {
  int r0 = blockIdx.x * 32;
  int tid = threadIdx.x;
  __shared__ float aS[32][130];
  for (int idx = tid; idx < 32 * 32; idx += 256) {
    int r = idx >> 5, dg = idx & 31;
    float4 v = ((const float4*)att)[(size_t)(r0 + r) * 32 + dg];
    aS[r][dg * 4 + 0] = v.x; aS[r][dg * 4 + 1] = v.y;
    aS[r][dg * 4 + 2] = v.z; aS[r][dg * 4 + 3] = v.w;
  }
  __syncthreads();
  int cg = tid & 15, rg = tid >> 4;
  float acc[2][8] = {};
  for (int d = 0; d < 128; d++) {
    float a0 = aS[rg * 2 + 0][d];
    float a1 = aS[rg * 2 + 1][d];
    float4 wlo = *(const float4*)(Wc + d * 128 + cg * 8);
    float4 whi = *(const float4*)(Wc + d * 128 + cg * 8 + 4);
    float w[8] = {wlo.x, wlo.y, wlo.z, wlo.w, whi.x, whi.y, whi.z, whi.w};
#pragma unroll
    for (int j = 0; j < 8; j++) {
      acc[0][j] += a0 * w[j];
      acc[1][j] += a1 * w[j];
    }
  }
#pragma unroll
  for (int i = 0; i < 2; i++) {
    float* dst = mh + (size_t)(r0 + rg * 2 + i) * 128 + cg * 8;
    *(float4*)dst = make_float4(acc[i][0], acc[i][1], acc[i][2], acc[i][3]);
    *(float4*)(dst + 4) = make_float4(acc[i][4], acc[i][5], acc[i][6], acc[i][7]);
  }
}

// ---------------------------------------------------------------------------
// gating: logits, top-2, softmax gates; hierarchical bucketing
// ---------------------------------------------------------------------------
__global__ __launch_bounds__(256) void k_gate(const float* __restrict__ mh,
                                              const float* __restrict__ wg,
                                              int* __restrict__ tlist,
                                              float* __restrict__ glist,
                                              int* __restrict__ cnt,
                                              float* __restrict__ imp) {
  int t0 = blockIdx.x * 256;
  int tid = threadIdx.x;
  __shared__ float wgS[128 * 8];
  __shared__ int lcnt[8];
  __shared__ float limp[8];
  __shared__ int lbase[8];
  for (int i = tid; i < 1024; i += 256) wgS[i] = wg[i];
  if (tid < 8) { lcnt[tid] = 0; limp[tid] = 0.f; }
  __syncthreads();
  int t = t0 + tid;
  bool ok = (t < NT);
  int i0 = 0, i1 = 0, r0 = 0, r1 = 0;
  float g0 = 0.f, g1 = 0.f;
  if (ok) {
    float lg[8] = {};
    const float* row = mh + (size_t)t * ND;
    for (int d = 0; d < ND; d += 4) {
      float4 x4 = *(const float4*)(row + d);
      float xs[4] = {x4.x, x4.y, x4.z, x4.w};
#pragma unroll
      for (int u = 0; u < 4; u++)
#pragma unroll
        for (int k = 0; k < 8; k++) lg[k] += xs[u] * wgS[(d + u) * 8 + k];
    }
    float v0 = -1e30f, v1 = -1e30f;
#pragma unroll
    for (int k = 0; k < 8; k++) {
      float l = lg[k];
      if (l > v0) { v1 = v0; i1 = i0; v0 = l; i0 = k; }
      else if (l > v1) { v1 = l; i1 = k; }
    }
    float ex = __expf(v1 - v0);
    float den = 1.0f + ex;
    g0 = 1.0f / den; g1 = ex / den;
    atomicAdd(&limp[i0], g0);
    atomicAdd(&limp[i1], g1);
    r0 = atomicAdd(&lcnt[i0], 1);
    r1 = atomicAdd(&lcnt[i1], 1);
  }
  __syncthreads();
  if (tid < 8) {
    lbase[tid] = atomicAdd(&cnt[tid], lcnt[tid]);
    atomicAdd(&imp[tid], limp[tid]);
  }
  __syncthreads();
  if (ok) {
    int p0 = lbase[i0] + r0;
    tlist[i0 * NT + p0] = t; glist[i0 * NT + p0] = g0;
    int p1 = lbase[i1] + r1;
    tlist[i1 * NT + p1] = t; glist[i1 * NT + p1] = g1;
  }
}

// ---------------------------------------------------------------------------
// Pack W1/W2 into fragment-ordered bf16 hi/lo for 16x16x32 MFMA B-operand.
// ---------------------------------------------------------------------------
__global__ __launch_bounds__(64) void k_wpack(const float* __restrict__ W1,
                                              const float* __restrict__ W2,
                                              unsigned short* __restrict__ w1h,
                                              unsigned short* __restrict__ w1l,
                                              unsigned short* __restrict__ w2h,
                                              unsigned short* __restrict__ w2l) {
  int bid = blockIdx.x;           // 8 experts * 256 tiles
  int e = bid >> 8;
  int t = bid & 255;
  int l = threadIdx.x;
  int kg = 4 * (l >> 4);
  if (t < 128) {
    int kt = t >> 5, nt = t & 31;
    const float* src = W1 + (size_t)e * 128 * 512;
    size_t base = ((((size_t)e * 4 + kt) * 32 + nt) * 64 + l) * 8;
    int n = nt * 16 + (l & 15);
#pragma unroll
    for (int j = 0; j < 8; j++) {
      int k = kt * 32 + kg + (j & 3) + ((j >> 2) << 4);
      float v = src[(size_t)k * 512 + n];
      unsigned short hi = f2bf(v);
      w1h[base + j] = hi;
      w1l[base + j] = f2bf(v - bf2f(hi));
    }
  } else {
    int tt = t - 128;
    int kt = tt >> 3, nt = tt & 7;
    const float* src = W2 + (size_t)e * 512 * 128;
    size_t base = ((((size_t)e * 16 + kt) * 8 + nt) * 64 + l) * 8;
    int n = nt * 16 + (l & 15);
#pragma unroll
    for (int j = 0; j < 8; j++) {
      int k = kt * 32 + kg + (j & 3) + ((j >> 2) << 4);
      float v = src[(size_t)k * 128 + n];
      unsigned short hi = f2bf(v);
      w2h[base + j] = hi;
      w2l[base + j] = f2bf(v - bf2f(hi));
    }
  }
}

// ---------------------------------------------------------------------------
// MoE expert FFN v11: z=2 half-split with sequential 2-chunk loop, packed A.
// ---------------------------------------------------------------------------
__global__ __launch_bounds__(256) void k_moe(const unsigned short* __restrict__ mhph,
                                             const unsigned short* __restrict__ mhpl,
                                             const unsigned short* __restrict__ w1h,
                                             const unsigned short* __restrict__ w1l,
                                             const unsigned short* __restrict__ w2h,
                                             const unsigned short* __restrict__ w2l,
                                             const float* __restrict__ b1,
                                             const float* __restrict__ b2,
                                             const int* __restrict__ tlist,
                                             const float* __restrict__ glist,
                                             const int* __restrict__ cnt,
                                             float* __restrict__ acc) {
  int e = blockIdx.y;
  int z = blockIdx.z;             // f-half 0..1
  int n = cnt[e];
  int t0 = blockIdx.x * 32;
  if (t0 >= n) return;
  int tid = threadIdx.x;
  int wq = tid >> 6;              // 0..3: N-quarter
  int l = tid & 63;
  int lr = l >> 4;
  __shared__ int rT[32];
  __shared__ float rG[32];
  __shared__ unsigned short hH[32][132];
  __shared__ unsigned short hL[32][132];
  if (tid < 32) {
    int ok = (t0 + tid) < n;
    rT[tid] = ok ? tlist[e * NT + t0 + tid] : -1;
    rG[tid] = ok ? glist[e * NT + t0 + tid] : 0.f;
  }
  __syncthreads();

  int kg = 4 * lr;
  bf16x8 Ah[2][4], Al[2][4];
#pragma unroll
  for (int m = 0; m < 2; m++) {
    int myrow = m * 16 + (l & 15);
    int mytok = rT[myrow];
#pragma unroll
    for (int kt = 0; kt < 4; kt++) {
      if (mytok >= 0) {
        size_t base = (((size_t)mytok * 4 + kt) * 4 + lr) * 8;
        Ah[m][kt] = *(const bf16x8*)(mhph + base);
        Al[m][kt] = *(const bf16x8*)(mhpl + base);
      } else {
        Ah[m][kt] = (bf16x8){0, 0, 0, 0, 0, 0, 0, 0};
        Al[m][kt] = (bf16x8){0, 0, 0, 0, 0, 0, 0, 0};
      }
    }
  }

  f32x4 zero4 = {0.f, 0.f, 0.f, 0.f};
  f32x4 yB[2][2] = {{zero4, zero4}, {zero4, zero4}};

  for (int cc = 0; cc < 2; cc++) {
    int c = z * 2 + cc;           // f-chunk 0..3
    f32x4 accA[2][2] = {{zero4, zero4}, {zero4, zero4}};
#pragma unroll
    for (int kt = 0; kt < 4; kt++) {
      bf16x8 bh[2], bl[2];
#pragma unroll
      for (int nt = 0; nt < 2; nt++) {
        int ntg = c * 8 + wq * 2 + nt;
        size_t fo = ((((size_t)e * 4 + kt) * 32 + ntg) * 64 + l) * 8;
        bh[nt] = *(const bf16x8*)(w1h + fo);
        bl[nt] = *(const bf16x8*)(w1l + fo);
      }
#pragma unroll
      for (int nt = 0; nt < 2; nt++)
#pragma unroll
        for (int m = 0; m < 2; m++) {
          accA[m][nt] = __builtin_amdgcn_mfma_f32_16x16x32_bf16(Ah[m][kt], bh[nt], accA[m][nt], 0, 0, 0);
          accA[m][nt] = __builtin_amdgcn_mfma_f32_16x16x32_bf16(Ah[m][kt], bl[nt], accA[m][nt], 0, 0, 0);
          accA[m][nt] = __builtin_amdgcn_mfma_f32_16x16x32_bf16(Al[m][kt], bh[nt], accA[m][nt], 0, 0, 0);
        }
    }
    __syncthreads();
#pragma unroll
    for (int nt = 0; nt < 2; nt++) {
      int nloc = wq * 32 + nt * 16 + (l & 15);
      float bv = b1[e * NFF + c * 128 + nloc];
#pragma unroll
      for (int m = 0; m < 2; m++)
#pragma unroll
        for (int r = 0; r < 4; r++) {
          int row = m * 16 + (l >> 4) * 4 + r;
          float hv = fmaxf(accA[m][nt][r] + bv, 0.f);
          unsigned short hi = f2bf(hv);
          hH[row][nloc] = hi;
          hL[row][nloc] = f2bf(hv - bf2f(hi));
        }
    }
    __syncthreads();
#pragma unroll
    for (int kt = 0; kt < 4; kt++) {
      int kb = kt * 32 + kg;
      bf16x8 ah2[2], al2[2];
#pragma unroll
      for (int m = 0; m < 2; m++) {
        int r2 = m * 16 + (l & 15);
        union { unsigned long long u[2]; bf16x8 v; } ua, ub;
        ua.u[0] = *(const unsigned long long*)(&hH[r2][kb]);
        ua.u[1] = *(const unsigned long long*)(&hH[r2][kb + 16]);
        ub.u[0] = *(const unsigned long long*)(&hL[r2][kb]);
        ub.u[1] = *(const unsigned long long*)(&hL[r2][kb + 16]);
        ah2[m] = ua.v; al2[m] = ub.v;
      }
      bf16x8 wh[2], wl[2];
#pragma unroll
      for (int nt = 0; nt < 2; nt++) {
        int ntg = wq * 2 + nt;
        size_t fo = ((((size_t)e * 16 + (c * 4 + kt)) * 8 + ntg) * 64 + l) * 8;
        wh[nt] = *(const bf16x8*)(w2h + fo);
        wl[nt] = *(const bf16x8*)(w2l + fo);
      }
#pragma unroll
      for (int nt = 0; nt < 2; nt++)
#pragma unroll
        for (int m = 0; m < 2; m++) {
          yB[m][nt] = __builtin_amdgcn_mfma_f32_16x16x32_bf16(ah2[m], wh[nt], yB[m][nt], 0, 0, 0);
          yB[m][nt] = __builtin_amdgcn_mfma_f32_16x16x32_bf16(ah2[m], wl[nt], yB[m][nt], 0, 0, 0);
          yB[m][nt] = __builtin_amdgcn_mfma_f32_16x16x32_bf16(al2[m], wh[nt], yB[m][nt], 0, 0, 0);
        }
    }
    __syncthreads();
  }
  float bsel = (z == 0) ? 1.f : 0.f;
#pragma unroll
  for (int nt = 0; nt < 2; nt++) {
    int d = (wq * 2 + nt) * 16 + (l & 15);
    float b2v = bsel * b2[e * ND + d];
#pragma unroll
    for (int m = 0; m < 2; m++)
#pragma unroll
      for (int r = 0; r < 4; r++) {
        int row = m * 16 + (l >> 4) * 4 + r;
        int tok = rT[row];
        if (tok >= 0)
          atomicAdd(acc + (size_t)tok * ND + d, rG[row] * (yB[m][nt][r] + b2v));
      }
  }
}

// ---------------------------------------------------------------------------
// moed_loss from importance
// ---------------------------------------------------------------------------
__global__ void k_loss(const float* __restrict__ imp, float* __restrict__ out) {
  if (threadIdx.x == 0 && blockIdx.x == 0) {
    float s = 0.f;
    for (int k = 0; k < 8; k++) s += imp[k];
    float mu = s * 0.125f;
    float v = 0.f;
    for (int k = 0; k < 8; k++) { float d = imp[k] - mu; v += d * d; }
    v *= (1.0f / 7.0f);
    out[8000000] = v / (mu * mu + 1e-10f);
  }
}

// ---------------------------------------------------------------------------
// added = mh + moe; instance-norm over G per (b,d); block = (b, 16-d chunk)
// ---------------------------------------------------------------------------
__global__ __launch_bounds__(256) void k_norm(const float* __restrict__ mh,
                                              const float* __restrict__ moe,
                                              const float* __restrict__ nw,
                                              const float* __restrict__ nb,
                                              float* __restrict__ outn) {
  int b = blockIdx.y;
  int d0 = blockIdx.x * 16;
  int tid = threadIdx.x;
  int dl = tid & 15, gs = tid >> 4;
  int d = d0 + dl;
  float s1 = 0.f, s2 = 0.f;
  for (int g = gs; g < NG; g += 16) {
    int idx = (b * NG + g) * ND + d;
    float x = mh[idx] + moe[idx];
    s1 += x; s2 += x * x;
  }
  __shared__ float r1[16][17], r2[16][17];
  __shared__ float sw[16], sb[16];
  r1[gs][dl] = s1; r2[gs][dl] = s2;
  __syncthreads();
  if (gs == 0) {
    float a = 0.f, q = 0.f;
    for (int k = 0; k < 16; k++) { a += r1[k][dl]; q += r2[k][dl]; }
    float mu = a * (1.0f / NG);
    float var = q * (1.0f / NG) - mu * mu;
    float rs = rsqrtf(var + 1e-5f);
    float w = nw[d] * rs;
    sw[dl] = w;
    sb[dl] = nb[d] - mu * w;
  }
  __syncthreads();
  float w = sw[dl], bb = sb[dl];
  for (int g = gs; g < NG; g += 16) {
    int idx = (b * NG + g) * ND + d;
    float x = mh[idx] + moe[idx];
    outn[idx] = x * w + bb;
  }
}

// ---------------------------------------------------------------------------
// final probs v3: split-bf16 MFMA score GEMM (A=normed, B=packed enc),
// tanh-clip + mask + no-max softmax; block = 32 g x 512 p, 4 waves = p-quarters.
// ---------------------------------------------------------------------------
__global__ __launch_bounds__(256) void k_probs(const float* __restrict__ normed,
                                               const unsigned short* __restrict__ eph,
                                               const unsigned short* __restrict__ epl,
                                               const float* __restrict__ mask,
                                               float* __restrict__ out) {
  int b = blockIdx.y;
  int g0 = blockIdx.x * 32;
  int tid = threadIdx.x;
  int wq = tid >> 6;              // p-quarter
  int l = tid & 63;
  int col = l & 15, lr = l >> 4;
  int kg = 4 * lr;
  __shared__ float ps[4][32];

  bf16x8 Ah[2][4], Al[2][4];
#pragma unroll
  for (int m = 0; m < 2; m++) {
    int g = g0 + m * 16 + col;
#pragma unroll
    for (int kt = 0; kt < 4; kt++) {
      float v[8];
      if (g < NG) {
        const float* row = normed + ((size_t)b * NG + g) * ND + kt * 32 + kg;
        float4 a = *(const float4*)(row);
        float4 bb = *(const float4*)(row + 16);
        v[0] = a.x; v[1] = a.y; v[2] = a.z; v[3] = a.w;
        v[4] = bb.x; v[5] = bb.y; v[6] = bb.z; v[7] = bb.w;
      } else {
#pragma unroll
        for (int j = 0; j < 8; j++) v[j] = 0.f;
      }
#pragma unroll
      for (int j = 0; j < 8; j++) {
        unsigned short hi = f2bf(v[j]);
        Ah[m][kt][j] = (short)hi;
        Al[m][kt][j] = (short)f2bf(v[j] - bf2f(hi));
      }
    }
  }

  f32x4 zero4 = {0.f, 0.f, 0.f, 0.f};
  f32x4 acc[2][8];
#pragma unroll
  for (int m = 0; m < 2; m++)
#pragma unroll
    for (int nt = 0; nt < 8; nt++) acc[m][nt] = zero4;

#pragma unroll
  for (int kt = 0; kt < 4; kt++) {
#pragma unroll
    for (int nt = 0; nt < 8; nt++) {
      int ntg = wq * 8 + nt;
      size_t fo = ((((size_t)b * 4 + kt) * 32 + ntg) * 64 + l) * 8;
      bf16x8 bh = *(const bf16x8*)(eph + fo);
      bf16x8 bl = *(const bf16x8*)(epl + fo);
#pragma unroll
      for (int m = 0; m < 2; m++) {
        acc[m][nt] = __builtin_amdgcn_mfma_f32_16x16x32_bf16(Ah[m][kt], bh, acc[m][nt], 0, 0, 0);
        acc[m][nt] = __builtin_amdgcn_mfma_f32_16x16x32_bf16(Ah[m][kt], bl, acc[m][nt], 0, 0, 0);
        acc[m][nt] = __builtin_amdgcn_mfma_f32_16x16x32_bf16(Al[m][kt], bh, acc[m][nt], 0, 0, 0);
      }
    }
  }

  float psum[2][4] = {};
#pragma unroll
  for (int m = 0; m < 2; m++)
#pragma unroll
    for (int nt = 0; nt < 8; nt++) {
      int p = wq * 128 + nt * 16 + col;
#pragma unroll
      for (int r = 0; r < 4; r++) {
        int g = g0 + m * 16 + 4 * lr + r;
        float s = acc[m][nt][r];
        float x = s * (1.0f / 11.313708498984761f);
        float e2 = __expf(2.0f * x);
        float th = (e2 - 1.0f) / (e2 + 1.0f);
        float v;
        if (p < NP && g < NG)
          v = 10.0f * th + mask[((size_t)b * NG + g) * NP + p];
        else
          v = -1e30f;
        float e = __expf(v);
        acc[m][nt][r] = e;
        psum[m][r] += e;
      }
    }
#pragma unroll
  for (int m = 0; m < 2; m++)
#pragma unroll
    for (int r = 0; r < 4; r++) {
      float s = psum[m][r];
      s += __shfl_xor(s, 1);
      s += __shfl_xor(s, 2);
      s += __shfl_xor(s, 4);
      s += __shfl_xor(s, 8);
      psum[m][r] = s;
    }
  if (col == 0) {
#pragma unroll
    for (int m = 0; m < 2; m++)
#pragma unroll
      for (int r = 0; r < 4; r++)
        ps[wq][m * 16 + 4 * lr + r] = psum[m][r];
  }
  __syncthreads();
#pragma unroll
  for (int m = 0; m < 2; m++)
#pragma unroll
    for (int r = 0; r < 4; r++) {
      int rowl = m * 16 + 4 * lr + r;
      float tot = ps[0][rowl] + ps[1][rowl] + ps[2][rowl] + ps[3][rowl];
      float inv = 1.0f / tot;
      int g = g0 + rowl;
      if (g < NG) {
#pragma unroll
        for (int nt = 0; nt < 8; nt++) {
          int p = wq * 128 + nt * 16 + col;
          if (p < NP)
            out[((size_t)b * NG + g) * NP + p] = acc[m][nt][r] * inv;
        }
      }
    }
}

// ---------------------------------------------------------------------------
extern "C" void kernel_launch(void* const* d_in, const int* in_sizes, int n_in,
                              void* d_out, int out_size, void* d_ws, size_t ws_size,
                              hipStream_t stream) {
  const float* graph    = (const float*)d_in[0];
  const float* capacity = (const float*)d_in[1];
  const float* mask     = (const float*)d_in[2];
  const float* enc      = (const float*)d_in[3];
  const float* Wq       = (const float*)d_in[4];
  const float* Wk       = (const float*)d_in[5];
  const float* Wv       = (const float*)d_in[6];
  const float* Wc       = (const float*)d_in[7];
  const float* wg       = (const float*)d_in[8];
  const float* W1       = (const float*)d_in[9];
  const float* b1       = (const float*)d_in[10];
  const float* W2       = (const float*)d_in[11];
  const float* b2       = (const float*)d_in[12];
  const float* nw       = (const float*)d_in[13];
  const float* nb       = (const float*)d_in[14];
  float* out = (float*)d_out;
  float* ws = (float*)d_ws;

  float* kbuf = ws;                  // 2,048,000 f  (later reused as moe accum)
  float* vbuf = ws + 2048000;        // 2,048,000 f  (later reused as normed)
  float* att  = ws + 4096000;        // 2,048,000 f  (later reused as eph)
  float* mh   = ws + 6144000;        // 2,048,000 f
  float* gq   = ws + 8192000;        // 4096 f
  int*   tlist = (int*)(ws + 8196096);   // 8*16000 int
  float* glist = ws + 8324096;           // 8*16000 f
  int*   cnt  = (int*)(ws + 8452096);    // 8 int
  float* imp  = ws + 8452104;            // 8 f
  // packed bf16 weights (each 524288 ushorts = 262144 float-slots)
  unsigned short* w1h = (unsigned short*)(ws + 8452112);
  unsigned short* w1l = (unsigned short*)(ws + 8714256);
  unsigned short* w2h = (unsigned short*)(ws + 8976400);
  unsigned short* w2l = (unsigned short*)(ws + 9238544);
  // transposed bf16 mask: dead after k_attn -> reused as packed mh hi/lo
  unsigned short* mT = (unsigned short*)(ws + 9500688);
  unsigned short* mhph = mT;
  unsigned short* mhpl = mT + 2048000;
  // packed enc fragments: eph aliases att region (after comb); epl at tail
  unsigned short* eph = (unsigned short*)att;
  unsigned short* epl = (unsigned short*)(ws + 13500688);

  k_maskT<<<dim3(16, 16, 32), 256, 0, stream>>>(mask, mT);
  k_wpack<<<2048, 64, 0, stream>>>(W1, W2, w1h, w1l, w2h, w2l);
  k_kv<<<1000, 256, 0, stream>>>(enc, Wk, Wv, kbuf, vbuf);
  k_graphq<<<32, 128, 0, stream>>>(graph, Wq, gq);
  k_attn<<<dim3(256, 2), 256, 0, stream>>>(kbuf, vbuf, capacity, gq, Wq, mT, att);
  // k/v consumed; reuse kbuf as MoE accumulator
  hipMemsetAsync(kbuf, 0, 2048000 * sizeof(float), stream);
  hipMemsetAsync(cnt, 0, 64, stream);  // cnt[8] + imp[8]
  k_comb<<<500, 256, 0, stream>>>(att, Wc, mh);
  // att consumed -> eph; mT consumed -> packed mh
  k_encpack<<<4096, 64, 0, stream>>>(enc, eph, epl);
  k_mhpack<<<500, 256, 0, stream>>>(mh, mhph, mhpl);
  k_gate<<<63, 256, 0, stream>>>(mh, wg, tlist, glist, cnt, imp);
  k_moe<<<dim3(500, 8, 2), 256, 0, stream>>>(mhph, mhpl, w1h, w1l, w2h, w2l,
                                             b1, b2, tlist, glist, cnt, kbuf);
  k_loss<<<1, 64, 0, stream>>>(imp, out);
  k_norm<<<dim3(8, 32), 256, 0, stream>>>(mh, kbuf, nw, nb, vbuf);
  k_probs<<<dim3(16, 32), 256, 0, stream>>>(vbuf, eph, epl, mask, out);
}